// Round 4
// baseline (366.320 us; speedup 1.0000x reference)
//
#include <hip/hip_runtime.h>
#include <math.h>

#define DIM    1024
#define HEADS  16
#define HDIM   64
#define HIDDEN 4096
#define BATCH  4
#define SEQ    1024
#define ROWS   (BATCH * SEQ)   // 4096

typedef short s16x8 __attribute__((ext_vector_type(8)));
typedef float f32x4 __attribute__((ext_vector_type(4)));

// ---- bf16 helpers ----
__device__ __forceinline__ float blo(unsigned int u) {
    union { unsigned int i; float f; } x; x.i = u << 16; return x.f;
}
__device__ __forceinline__ float bhi(unsigned int u) {
    union { unsigned int i; float f; } x; x.i = u & 0xffff0000u; return x.f;
}
__device__ __forceinline__ unsigned short f2b(float f) {   // round-to-nearest-even
    union { float f; unsigned int i; } x; x.f = f;
    unsigned int r = x.i + 0x7fffu + ((x.i >> 16) & 1u);
    return (unsigned short)(r >> 16);
}

// ---- fast exact-GELU: branchless A&S 7.1.26 erf, max |err| ~1.5e-7 ----
__device__ __forceinline__ float gelu_f(float x) {
    float z  = fabsf(x) * 0.70710678118f;
    float t  = __builtin_amdgcn_rcpf(__builtin_fmaf(0.3275911f, z, 1.0f));
    float p  = ((((1.061405429f * t - 1.453152027f) * t + 1.421413741f) * t
                 - 0.284496736f) * t + 0.254829592f) * t;
    float e  = exp2f(-0.72134752f * x * x);       // exp(-z^2), z^2 = x^2/2
    float w  = 0.5f * p * e;                      // 0.5*(1 - erf(|z|))
    float phi = (x >= 0.0f) ? (1.0f - w) : w;     // Phi(x) = 0.5*(1+erf(z))
    return x * phi;
}

// ---- TILED operand layout: chunk = 16 rows x 32 k, 1KB contiguous, MFMA lane order ----
__device__ __forceinline__ size_t tidx(int row, int k, int Kdim) {
    return ((size_t)(row >> 4) * (Kdim >> 5) + (k >> 5)) * 512
         + (size_t)(((k & 31) >> 3) * 128 + (row & 15) * 8 + (k & 7));
}

// ---- async global->LDS, 16B/lane ----
__device__ __forceinline__ void gload_lds16(const void* g, void* l) {
    __builtin_amdgcn_global_load_lds(
        (const __attribute__((address_space(1))) unsigned int*)g,
        (__attribute__((address_space(3))) unsigned int*)l, 16, 0, 0);
}

// ---------------- prep: LN1 rows + all 4 weight convert/transpose, ONE launch ----------------
__global__ __launch_bounds__(256) void prep_kernel(const float* __restrict__ x,
                                                   const float* __restrict__ g,
                                                   const float* __restrict__ b,
                                                   unsigned short* __restrict__ lnout,
                                                   const float* __restrict__ qkv_w,
                                                   unsigned short* __restrict__ wT_qkv,
                                                   const float* __restrict__ proj_w,
                                                   unsigned short* __restrict__ wT_proj,
                                                   const float* __restrict__ fc1_w,
                                                   unsigned short* __restrict__ wT_fc1,
                                                   const float* __restrict__ fc2_w,
                                                   unsigned short* __restrict__ wT_fc2) {
    __shared__ float red1[256], red2[256];
    __shared__ unsigned short T[64][68];
    const int bid = blockIdx.x;
    const int t = threadIdx.x;

    if (bid < ROWS) {
        int row = bid;
        const float* xr = x + (size_t)row * DIM;
        float4 v = *((const float4*)(xr + t * 4));
        float s  = v.x + v.y + v.z + v.w;
        float ss = v.x * v.x + v.y * v.y + v.z * v.z + v.w * v.w;
        red1[t] = s; red2[t] = ss;
        __syncthreads();
        for (int off = 128; off > 0; off >>= 1) {
            if (t < off) { red1[t] += red1[t + off]; red2[t] += red2[t + off]; }
            __syncthreads();
        }
        float mu   = red1[0] * (1.0f / DIM);
        float var  = red2[0] * (1.0f / DIM) - mu * mu;
        float rstd = rsqrtf(var + 1e-5f);
        float4 gv = *((const float4*)(g + t * 4));
        float4 bv = *((const float4*)(b + t * 4));
        ushort4 o;
        o.x = f2b((v.x - mu) * rstd * gv.x + bv.x);
        o.y = f2b((v.y - mu) * rstd * gv.y + bv.y);
        o.z = f2b((v.z - mu) * rstd * gv.z + bv.z);
        o.w = f2b((v.w - mu) * rstd * gv.w + bv.w);
        *((ushort4*)(lnout + tidx(row, t * 4, DIM))) = o;
    } else {
        int tt = bid - ROWS;
        const float* W; unsigned short* Wt; int K, N, bx, by;
        if (tt < 768) {
            W = qkv_w; Wt = wT_qkv; K = DIM; N = 3 * DIM; bx = tt % 48; by = tt / 48;
        } else if (tt < 768 + 256) {
            tt -= 768;
            W = proj_w; Wt = wT_proj; K = DIM; N = DIM; bx = tt % 16; by = tt / 16;
        } else if (tt < 768 + 256 + 1024) {
            tt -= 768 + 256;
            W = fc1_w; Wt = wT_fc1; K = DIM; N = HIDDEN; bx = tt % 64; by = tt / 64;
        } else {
            tt -= 768 + 256 + 1024;
            W = fc2_w; Wt = wT_fc2; K = HIDDEN; N = DIM; bx = tt % 16; by = tt / 16;
        }
        int n0 = bx * 64, k0 = by * 64;
        int cr = t >> 4;
        int cc = (t & 15) * 4;
        #pragma unroll
        for (int r = 0; r < 4; ++r) {
            int kk = cr + 16 * r;
            float4 v = *((const float4*)(W + (size_t)(k0 + kk) * N + n0 + cc));
            T[cc + 0][kk] = f2b(v.x);
            T[cc + 1][kk] = f2b(v.y);
            T[cc + 2][kk] = f2b(v.z);
            T[cc + 3][kk] = f2b(v.w);
        }
        __syncthreads();
        {
            int nn = t >> 2;
            int kg = (t & 3) * 16;
            #pragma unroll
            for (int p = 0; p < 2; ++p) {
                int k8 = kg + p * 8;
                ushort4 lo = *((ushort4*)&T[nn][k8]);
                ushort4 hi = *((ushort4*)&T[nn][k8 + 4]);
                unsigned short* dst = Wt + tidx(n0 + nn, k0 + k8, K);
                *((ushort4*)dst)       = lo;
                *((ushort4*)(dst + 4)) = hi;
            }
        }
    }
}

// -------- Fused: x1 = x + proj_b + p0 + p1 (fp32 -> xout), then LN -> tiled bf16 --------
__global__ __launch_bounds__(256) void reduce_ln(const unsigned short* __restrict__ p0,
                                                 const unsigned short* __restrict__ p1,
                                                 const float* __restrict__ x,
                                                 const float* __restrict__ bias,
                                                 const float* __restrict__ g,
                                                 const float* __restrict__ b,
                                                 float* __restrict__ xout,
                                                 unsigned short* __restrict__ lnout) {
    int row = blockIdx.x;
    int t = threadIdx.x;
    size_t i = (size_t)row * DIM + t * 4;
    float4 xv = *((const float4*)(x + i));
    float4 bi = *((const float4*)(bias + t * 4));
    uint2 w0 = *((const uint2*)(p0 + i));
    uint2 w1 = *((const uint2*)(p1 + i));
    float4 v;
    v.x = xv.x + bi.x + blo(w0.x) + blo(w1.x);
    v.y = xv.y + bi.y + bhi(w0.x) + bhi(w1.x);
    v.z = xv.z + bi.z + blo(w0.y) + blo(w1.y);
    v.w = xv.w + bi.w + bhi(w0.y) + bhi(w1.y);
    *((float4*)(xout + i)) = v;

    float s  = v.x + v.y + v.z + v.w;
    float ss = v.x * v.x + v.y * v.y + v.z * v.z + v.w * v.w;
    __shared__ float red1[256], red2[256];
    red1[t] = s; red2[t] = ss;
    __syncthreads();
    for (int off = 128; off > 0; off >>= 1) {
        if (t < off) { red1[t] += red1[t + off]; red2[t] += red2[t + off]; }
        __syncthreads();
    }
    float mu   = red1[0] * (1.0f / DIM);
    float var  = red2[0] * (1.0f / DIM) - mu * mu;
    float rstd = rsqrtf(var + 1e-5f);
    float4 gv = *((const float4*)(g + t * 4));
    float4 bv = *((const float4*)(b + t * 4));
    ushort4 o;
    o.x = f2b((v.x - mu) * rstd * gv.x + bv.x);
    o.y = f2b((v.y - mu) * rstd * gv.y + bv.y);
    o.z = f2b((v.z - mu) * rstd * gv.z + bv.z);
    o.w = f2b((v.w - mu) * rstd * gv.w + bv.w);
    *((ushort4*)(lnout + tidx(row, t * 4, DIM))) = o;
}

// ---------------- 128-tile MFMA GEMM, double-buffered LDS pipeline ----------------
// Per K-step: issue stage(t+1) -> buf^1, compute buf (32 MFMA), ONE __syncthreads.
// The vmcnt(0) drain inside __syncthreads happens AFTER compute, so the staged
// loads had ~600cy to land -> stall ~0 (vs old stage->drain->compute: full latency).
// fuse: 0 = bias, bf16 TILED out (+V scatter); 1 = bias+GELU tiled; 2 = bias+residual
// fp32 out (out = acc + bias + add); 3 = split-K partial, plain bf16 row-major.
__global__ __launch_bounds__(256, 2) void mfma_gemm(const unsigned short* __restrict__ A,
                                                 const unsigned short* __restrict__ Bt,
                                                 const float* __restrict__ bias,
                                                 const float* __restrict__ add,
                                                 void* __restrict__ Cout,
                                                 unsigned short* __restrict__ vt,
                                                 unsigned short* __restrict__ p0,
                                                 unsigned short* __restrict__ p1,
                                                 int M, int N, int K, int Ksplit, int fuse) {
    __shared__ __align__(16) short Asm[2][8192];
    __shared__ __align__(16) short Bsm[2][8192];

    const int tid  = threadIdx.x;
    const int lane = tid & 63;
    const int wave = tid >> 6;
    const int wy = wave >> 1, wx = wave & 1;
    const int lr = lane & 15;
    const int lq = lane >> 4;

    // XCD-L2 supergroup remap (groups of 8 n-tiles, m fastest within group)
    int m_t, n_t;
    {
        const int mt = gridDim.x, ntl = gridDim.y, G = 8;
        if (ntl > G) {
            int lin = blockIdx.y * mt + blockIdx.x;
            int gsz = mt * G;
            int grp = lin / gsz;
            int rem = lin - grp * gsz;
            m_t = rem % mt;
            n_t = grp * G + rem / mt;
        } else { m_t = blockIdx.x; n_t = blockIdx.y; }
    }
    const int m0 = m_t * 128, n0 = n_t * 128;
    const int kbase = blockIdx.z * Ksplit;
    const int kch = K >> 5;

    f32x4 acc[4][4];
    #pragma unroll
    for (int i = 0; i < 4; ++i)
        #pragma unroll
        for (int j = 0; j < 4; ++j)
            acc[i][j] = (f32x4){0.f, 0.f, 0.f, 0.f};

    const unsigned short* ag[4]; const unsigned short* bg[4];
    #pragma unroll
    for (int j = 0; j < 4; ++j) {
        int cid = wave * 4 + j;
        int mb  = cid >> 1;
        int kc  = cid & 1;
        ag[j] = A  + ((size_t)((m0 >> 4) + mb) * kch + (kbase >> 5) + kc) * 512 + lane * 8;
        bg[j] = Bt + ((size_t)((n0 >> 4) + mb) * kch + (kbase >> 5) + kc) * 512 + lane * 8;
    }

#define STAGE(buf) { \
    _Pragma("unroll") for (int j_ = 0; j_ < 4; ++j_) { \
        gload_lds16(ag[j_], &Asm[buf][(wave * 4 + j_) * 512]); \
        gload_lds16(bg[j_], &Bsm[buf][(wave * 4 + j_) * 512]); \
        ag[j_] += 1024; bg[j_] += 1024; \
    } }
#define COMPUTE(buf) { \
    _Pragma("unroll") for (int kc_ = 0; kc_ < 2; ++kc_) { \
        s16x8 af[4], bf[4]; \
        _Pragma("unroll") for (int i_ = 0; i_ < 4; ++i_) \
            af[i_] = *((const s16x8*)&Asm[buf][((wy * 4 + i_) * 2 + kc_) * 512 + lane * 8]); \
        _Pragma("unroll") for (int j_ = 0; j_ < 4; ++j_) \
            bf[j_] = *((const s16x8*)&Bsm[buf][((wx * 4 + j_) * 2 + kc_) * 512 + lane * 8]); \
        _Pragma("unroll") for (int i_ = 0; i_ < 4; ++i_) \
            _Pragma("unroll") for (int j_ = 0; j_ < 4; ++j_) \
                acc[i_][j_] = __builtin_amdgcn_mfma_f32_16x16x32_bf16(af[i_], bf[j_], acc[i_][j_], 0, 0, 0); \
    } }

    // prologue: tile 0 -> buf0
    STAGE(0);
    __syncthreads();
    // main loop: NITER always even (8/16/64); static buffer indices
    for (int k0 = 0; k0 < Ksplit; k0 += 128) {
        STAGE(1);                                 // tile t+1 (always valid: last pair stages final tile)
        COMPUTE(0);                               // tile t
        __syncthreads();
        if (k0 + 128 < Ksplit) STAGE(0);          // tile t+2
        COMPUTE(1);                               // tile t+1
        __syncthreads();
    }
#undef STAGE
#undef COMPUTE

    // ======================= epilogue =======================
    // All LDS dead after final barrier; wave-private regions, no barriers needed.
    short* Wl = (wave < 2 ? (short*)Asm : (short*)Bsm) + (wave & 1) * 4096;   // 8KB bf16

    if (fuse == 0 && vt && (n0 + wx * 64) >= 2 * DIM) {
        // V-scatter path (QKV only; wave-uniform): scalar stores (special layout)
        #pragma unroll
        for (int j = 0; j < 4; ++j) {
            int col = n0 + wx * 64 + j * 16 + lr;
            float bi = bias[col];
            #pragma unroll
            for (int i = 0; i < 4; ++i) {
                int row0 = m0 + wy * 64 + i * 16 + lq * 4;
                #pragma unroll
                for (int r = 0; r < 4; ++r) {
                    float val = acc[i][j][r] + bi;
                    int row = row0 + r;
                    int b_ = row >> 10, tok = row & 1023;
                    int hd = col - 2 * DIM, h_ = hd >> 6, d = hd & 63;
                    size_t o = (size_t)(b_ * 16 + h_) * 65536
                             + ((size_t)(d >> 4) * 32 + (tok >> 5)) * 512
                             + ((tok & 31) >> 3) * 128 + (d & 15) * 8 + (tok & 7);
                    vt[o] = f2b(val);
                }
            }
        }
    } else if (fuse == 2) {
        // fp32 residual out: stage fp32 in wave-private 16KB, coalesced float4 out
        float* W32 = (float*)((wave < 2 ? (short*)Asm : (short*)Bsm) + (wave & 1) * 8192);
        #pragma unroll
        for (int j = 0; j < 4; ++j) {
            float bi = bias[n0 + wx * 64 + j * 16 + lr];
            #pragma unroll
            for (int i = 0; i < 4; ++i) {
                #pragma unroll
                for (int r = 0; r < 4; ++r) {
                    int rowL = i * 16 + lq * 4 + r;
                    int colL = (j * 16 + lr) ^ ((rowL & 3) << 4);
                    W32[rowL * 64 + colL] = acc[i][j][r] + bi;
                }
            }
        }
        float* orow = (float*)Cout + (size_t)(m0 + wy * 64) * N + n0 + wx * 64;
        const float* arow = add + (size_t)(m0 + wy * 64) * N + n0 + wx * 64;
        #pragma unroll
        for (int pass = 0; pass < 16; ++pass) {
            int rowL = pass * 4 + lq;
            int pos = (lr * 4) ^ ((rowL & 3) << 4);
            float4 v = *((float4*)&W32[rowL * 64 + pos]);
            size_t off = (size_t)rowL * N + lr * 4;
            float4 a = *((const float4*)&arow[off]);
            v.x += a.x; v.y += a.y; v.z += a.z; v.w += a.w;
            *((float4*)&orow[off]) = v;
        }
    } else if (fuse == 3) {
        // row-major partials: stage [64][64] in LDS (col ^= (rowL&7)<<3), b128 out
        #pragma unroll
        for (int j = 0; j < 4; ++j) {
            #pragma unroll
            for (int i = 0; i < 4; ++i) {
                #pragma unroll
                for (int r = 0; r < 4; ++r) {
                    int rowL = i * 16 + lq * 4 + r;
                    int colL = (j * 16 + lr) ^ ((rowL & 7) << 3);
                    Wl[rowL * 64 + colL] = (short)f2b(acc[i][j][r]);
                }
            }
        }
        unsigned short* P = (blockIdx.z == 0) ? p0 : p1;
        unsigned short* Prow = P + (size_t)(m0 + wy * 64 + lane) * N + n0 + wx * 64;
        #pragma unroll
        for (int c = 0; c < 8; ++c) {
            int colr = (c * 8) ^ ((lane & 7) << 3);
            s16x8 v = *((const s16x8*)&Wl[lane * 64 + colr]);
            *((s16x8*)&Prow[c * 8]) = v;
        }
    } else {
        // tiled bf16 out (fuse 0 Q/K region, fuse 1): stage 8 chunks x 512, b128 out
        #pragma unroll
        for (int j = 0; j < 4; ++j) {
            float bi = bias[n0 + wx * 64 + j * 16 + lr];
            #pragma unroll
            for (int i = 0; i < 4; ++i) {
                #pragma unroll
                for (int r = 0; r < 4; ++r) {
                    float val = acc[i][j][r] + bi;
                    if (fuse == 1) val = gelu_f(val);
                    int colL = (j & 1) * 16 + lr;
                    int hi = colL >> 3;
                    int pos = hi * 128 + (lq * 4 + r) * 8 + (lr & 7);
                    pos ^= ((pos >> 7) & 3) << 3;
                    Wl[(i * 2 + (j >> 1)) * 512 + pos] = (short)f2b(val);
                }
            }
        }
        const size_t rc0 = (size_t)((m0 + wy * 64) >> 4);
        const size_t cc0 = (size_t)((n0 + wx * 64) >> 5);
        const size_t nch = (size_t)(N >> 5);
        #pragma unroll
        for (int c = 0; c < 8; ++c) {
            int raddr = lane * 8;
            raddr ^= ((raddr >> 7) & 3) << 3;
            s16x8 v = *((const s16x8*)&Wl[c * 512 + raddr]);
            size_t chunk = (rc0 + (c >> 1)) * nch + cc0 + (c & 1);
            *((s16x8*)&((unsigned short*)Cout)[chunk * 512 + lane * 8]) = v;
        }
    }
}

// ------------- MFMA flash attention, no-max softmax + ones-column row sums -------------
__global__ __launch_bounds__(256) void fattn_mfma(const unsigned short* __restrict__ qkv,
                                                  const unsigned short* __restrict__ Vt,
                                                  unsigned short* __restrict__ out) {
    __shared__ __align__(16) short Qs[8192];
    __shared__ __align__(16) short Ks[4096];
    __shared__ __align__(16) short Vs[4096];
    __shared__ __align__(16) short Ps[128 * 72];
    __shared__ __align__(16) short OnesB[512];   // B-frag: col0 = 1.0, rest 0

    const int tid = threadIdx.x, lane = tid & 63, wave = tid >> 6;
    const int lr = lane & 15, lq = lane >> 4;
    const int L = blockIdx.x;
    const int bh = (L & 7) + 8 * (L >> 6);
    const int b = bh >> 4, h = bh & 15;
    const int q0 = ((L >> 3) & 7) * 128;

    {
        s16x8 z = (s16x8){0,0,0,0,0,0,0,0};
        if (lr == 0) { z[0] = (short)0x3F80; z[1] = (short)0x3F80;
                       z[2] = (short)0x3F80; z[3] = (short)0x3F80;
                       z[4] = (short)0x3F80; z[5] = (short)0x3F80;
                       z[6] = (short)0x3F80; z[7] = (short)0x3F80; }
        if (wave == 0) *((s16x8*)&OnesB[lane * 8]) = z;
    }

    #pragma unroll
    for (int j = 0; j < 4; ++j) {
        int cid = wave * 4 + j;
        const unsigned short* g = qkv + ((size_t)(((b * SEQ + q0) >> 4) + (cid >> 1)) * 96
                                         + 2 * h + (cid & 1)) * 512 + lane * 8;
        gload_lds16(g, &Qs[cid * 512]);
    }

    const unsigned short* kg_[2]; const unsigned short* vg_[2];
    short *kl_[2], *vl_[2];
    #pragma unroll
    for (int j = 0; j < 2; ++j) {
        int cid = wave * 2 + j;
        kg_[j] = qkv + ((size_t)(((b * SEQ) >> 4) + (cid >> 1)) * 96
                        + 32 + 2 * h + (cid & 1)) * 512 + lane * 8;
        vg_[j] = Vt + (size_t)bh * 65536
                 + ((size_t)(cid >> 1) * 32 + (cid & 1)) * 512 + lane * 8;
        kl_[j] = &Ks[cid * 512];
        vl_[j] = &Vs[cid * 512];
    }

    f32x4 osum[2][5];
    #pragma unroll
    for (int i = 0; i < 2; ++i)
        #pragma unroll
        for (int d = 0; d < 5; ++d)
            osum[i][d] = (f32x4){0.f, 0.f, 0.f, 0.f};

    const float c = 0.125f * 1.44269504f;   // scale * log2(e)

    for (int k0 = 0; k0 < SEQ; k0 += 64) {
        #pragma unroll
        for (int j = 0; j < 2; ++j) {
            gload_lds16(kg_[j], kl_[j]);
            gload_lds16(vg_[j], vl_[j]);
            kg_[j] += 4 * 96 * 512;
            vg_[j] += 1024;
        }
        __syncthreads();

        f32x4 s[2][4];
        #pragma unroll
        for (int i = 0; i < 2; ++i)
            #pragma unroll
            for (int jb = 0; jb < 4; ++jb)
                s[i][jb] = (f32x4){0.f, 0.f, 0.f, 0.f};
        #pragma unroll
        for (int kc = 0; kc < 2; ++kc) {
            s16x8 aq0 = *((const s16x8*)&Qs[(wave * 4 + 0 + kc) * 512 + lane * 8]);
            s16x8 aq1 = *((const s16x8*)&Qs[(wave * 4 + 2 + kc) * 512 + lane * 8]);
            #pragma unroll
            for (int jb = 0; jb < 4; ++jb) {
                s16x8 bk = *((const s16x8*)&Ks[(jb * 2 + kc) * 512 + lane * 8]);
                s[0][jb] = __builtin_amdgcn_mfma_f32_16x16x32_bf16(aq0, bk, s[0][jb], 0, 0, 0);
                s[1][jb] = __builtin_amdgcn_mfma_f32_16x16x32_bf16(aq1, bk, s[1][jb], 0, 0, 0);
            }
        }

        #pragma unroll
        for (int i = 0; i < 2; ++i)
            #pragma unroll
            for (int r = 0; r < 4; ++r) {
                int prow = (wave * 2 + i) * 16 + lq * 4 + r;
                #pragma unroll
                for (int jb = 0; jb < 4; ++jb)
                    Ps[prow * 72 + jb * 16 + lr] = (short)f2b(exp2f(s[i][jb][r] * c));
            }

        #pragma unroll
        for (int kc = 0; kc < 2; ++kc) {
            s16x8 ap0 = *((const s16x8*)&Ps[((wave * 2 + 0) * 16 + lr) * 72 + kc * 32 + lq * 8]);
            s16x8 ap1 = *((const s16x8*)&Ps[((wave * 2 + 1) * 16 + lr) * 72 + kc * 32 + lq * 8]);
            #pragma unroll
            for (int db = 0; db < 4; ++db) {
                s16x8 bv = *((const s16x8*)&Vs[(db * 2 + kc) * 512 + lane * 8]);
                osum[0][db] = __builtin_amdgcn_mfma_f32_16x16x32_bf16(ap0, bv, osum[0][db], 0, 0, 0);
                osum[1][db] = __builtin_amdgcn_mfma_f32_16x16x32_bf16(ap1, bv, osum[1][db], 0, 0, 0);
            }
            s16x8 bo = *((const s16x8*)&OnesB[lane * 8]);
            osum[0][4] = __builtin_amdgcn_mfma_f32_16x16x32_bf16(ap0, bo, osum[0][4], 0, 0, 0);
            osum[1][4] = __builtin_amdgcn_mfma_f32_16x16x32_bf16(ap1, bo, osum[1][4], 0, 0, 0);
        }
        __syncthreads();
    }

    #pragma unroll
    for (int i = 0; i < 2; ++i) {
        int qrow = q0 + (wave * 2 + i) * 16 + lq * 4;
        #pragma unroll
        for (int r = 0; r < 4; ++r) {
            float lsum = __shfl(osum[i][4][r], lane & 48, 64);
            float inv = 1.0f / lsum;
            int row = b * SEQ + qrow + r;
            #pragma unroll
            for (int db = 0; db < 4; ++db)
                out[tidx(row, h * 64 + db * 16 + lr, DIM)] = f2b(osum[i][db][r] * inv);
        }
    }
}

extern "C" void kernel_launch(void* const* d_in, const int* in_sizes, int n_in,
                              void* d_out, int out_size, void* d_ws, size_t ws_size,
                              hipStream_t stream) {
    const float* x      = (const float*)d_in[0];
    const float* ln1_g  = (const float*)d_in[1];
    const float* ln1_b  = (const float*)d_in[2];
    const float* ln2_g  = (const float*)d_in[3];
    const float* ln2_b  = (const float*)d_in[4];
    const float* qkv_w  = (const float*)d_in[5];
    const float* qkv_b  = (const float*)d_in[6];
    const float* proj_w = (const float*)d_in[7];
    const float* proj_b = (const float*)d_in[8];
    const float* fc1_w  = (const float*)d_in[9];
    const float* fc1_b  = (const float*)d_in[10];
    const float* fc2_w  = (const float*)d_in[11];
    const float* fc2_b  = (const float*)d_in[12];
    float* out = (float*)d_out;

    // workspace layout (MiB), 72 total — liveness-packed
    char* ws = (char*)d_ws;
    unsigned short* wT_fc2  = (unsigned short*)(ws);
    unsigned short* wT_qkv  = (unsigned short*)(ws + (8u  << 20));
    unsigned short* wT_proj = (unsigned short*)(ws + (14u << 20));
    unsigned short* qkvbuf  = (unsigned short*)(ws + (16u << 20));
    unsigned short* Vt      = (unsigned short*)(ws + (40u << 20));
    unsigned short* attnout = (unsigned short*)(ws + (48u << 20));
    unsigned short* lnout   = (unsigned short*)(ws + (56u << 20));
    unsigned short* wT_fc1  = (unsigned short*)(ws + (64u << 20));
    unsigned short* gelu    = (unsigned short*)(ws + (16u << 20));
    unsigned short* pp0 = (unsigned short*)(ws + (16u << 20));
    unsigned short* pp1 = (unsigned short*)(ws + (24u << 20));

    // 0+1) prep: LN1(x) -> lnout tiled  AND  all 4 weight converts (one launch)
    prep_kernel<<<ROWS + 3072, 256, 0, stream>>>(
        x, ln1_g, ln1_b, lnout,
        qkv_w, wT_qkv, proj_w, wT_proj, fc1_w, wT_fc1, fc2_w, wT_fc2);
    // 2) qkv = h1 @ qkv_w + qkv_b -> Q,K tiled; V -> Vt tiled (fused transpose)
    mfma_gemm<<<dim3(ROWS / 128, 3 * DIM / 128, 1), 256, 0, stream>>>(
        lnout, wT_qkv, qkv_b, nullptr, qkvbuf, Vt, nullptr, nullptr,
        ROWS, 3 * DIM, DIM, DIM, 0);
    // 3) o = mfma flash attention -> attnout tiled
    fattn_mfma<<<(SEQ / 128) * BATCH * HEADS, 256, 0, stream>>>(qkvbuf, Vt, attnout);
    // 4) proj split-K (S=2): partials = o @ proj_w (plain bf16)
    mfma_gemm<<<dim3(ROWS / 128, DIM / 128, 2), 256, 0, stream>>>(
        attnout, wT_proj, proj_b, nullptr, nullptr, nullptr, pp0, pp1,
        ROWS, DIM, DIM, DIM / 2, 3);
    // 4b+5) x1 = x + sum + proj_b -> d_out; h2 = LN2(x1) -> lnout tiled  (FUSED)
    reduce_ln<<<ROWS, 256, 0, stream>>>(pp0, pp1, x, proj_b, ln2_g, ln2_b, out, lnout);
    // 6) g = gelu(h2 @ fc1_w + fc1_b) -> bf16 tiled  [4096 x 4096]
    mfma_gemm<<<dim3(ROWS / 128, HIDDEN / 128, 1), 256, 0, stream>>>(
        lnout, wT_fc1, fc1_b, nullptr, gelu, nullptr, nullptr, nullptr,
        ROWS, HIDDEN, DIM, DIM, 1);
    // 7) FC2 UNSPLIT (K=4096, 64 pipelined iters, 256 blocks):
    //    out = x1 + fc2_b + g @ fc2_w  (fp32, in-place residual; no partials, no reduce)
    mfma_gemm<<<dim3(ROWS / 128, DIM / 128, 1), 256, 0, stream>>>(
        gelu, wT_fc2, fc2_b, out, out, nullptr, nullptr, nullptr,
        ROWS, DIM, HIDDEN, HIDDEN, 2);
}

// Round 5
// 343.432 us; speedup vs baseline: 1.0666x; 1.0666x over previous
//
#include <hip/hip_runtime.h>
#include <math.h>

#define DIM    1024
#define HEADS  16
#define HDIM   64
#define HIDDEN 4096
#define BATCH  4
#define SEQ    1024
#define ROWS   (BATCH * SEQ)   // 4096

typedef short s16x8 __attribute__((ext_vector_type(8)));
typedef float f32x4 __attribute__((ext_vector_type(4)));

// ---- bf16 helpers ----
__device__ __forceinline__ float blo(unsigned int u) {
    union { unsigned int i; float f; } x; x.i = u << 16; return x.f;
}
__device__ __forceinline__ float bhi(unsigned int u) {
    union { unsigned int i; float f; } x; x.i = u & 0xffff0000u; return x.f;
}
__device__ __forceinline__ unsigned short f2b(float f) {   // round-to-nearest-even
    union { float f; unsigned int i; } x; x.f = f;
    unsigned int r = x.i + 0x7fffu + ((x.i >> 16) & 1u);
    return (unsigned short)(r >> 16);
}

// ---- fast exact-GELU: branchless A&S 7.1.26 erf, max |err| ~1.5e-7 ----
__device__ __forceinline__ float gelu_f(float x) {
    float z  = fabsf(x) * 0.70710678118f;
    float t  = __builtin_amdgcn_rcpf(__builtin_fmaf(0.3275911f, z, 1.0f));
    float p  = ((((1.061405429f * t - 1.453152027f) * t + 1.421413741f) * t
                 - 0.284496736f) * t + 0.254829592f) * t;
    float e  = exp2f(-0.72134752f * x * x);       // exp(-z^2), z^2 = x^2/2
    float w  = 0.5f * p * e;                      // 0.5*(1 - erf(|z|))
    float phi = (x >= 0.0f) ? (1.0f - w) : w;     // Phi(x) = 0.5*(1+erf(z))
    return x * phi;
}

// ---- TILED operand layout: chunk = 16 rows x 32 k, 1KB contiguous, MFMA lane order ----
__device__ __forceinline__ size_t tidx(int row, int k, int Kdim) {
    return ((size_t)(row >> 4) * (Kdim >> 5) + (k >> 5)) * 512
         + (size_t)(((k & 31) >> 3) * 128 + (row & 15) * 8 + (k & 7));
}

// ---- async global->LDS, 16B/lane ----
__device__ __forceinline__ void gload_lds16(const void* g, void* l) {
    __builtin_amdgcn_global_load_lds(
        (const __attribute__((address_space(1))) unsigned int*)g,
        (__attribute__((address_space(3))) unsigned int*)l, 16, 0, 0);
}

// ---------------- prep: LN1 rows + all 4 weight convert/transpose, ONE launch ----------------
__global__ __launch_bounds__(256) void prep_kernel(const float* __restrict__ x,
                                                   const float* __restrict__ g,
                                                   const float* __restrict__ b,
                                                   unsigned short* __restrict__ lnout,
                                                   const float* __restrict__ qkv_w,
                                                   unsigned short* __restrict__ wT_qkv,
                                                   const float* __restrict__ proj_w,
                                                   unsigned short* __restrict__ wT_proj,
                                                   const float* __restrict__ fc1_w,
                                                   unsigned short* __restrict__ wT_fc1,
                                                   const float* __restrict__ fc2_w,
                                                   unsigned short* __restrict__ wT_fc2) {
    __shared__ float red1[256], red2[256];
    __shared__ unsigned short T[64][68];
    const int bid = blockIdx.x;
    const int t = threadIdx.x;

    if (bid < ROWS) {
        int row = bid;
        const float* xr = x + (size_t)row * DIM;
        float4 v = *((const float4*)(xr + t * 4));
        float s  = v.x + v.y + v.z + v.w;
        float ss = v.x * v.x + v.y * v.y + v.z * v.z + v.w * v.w;
        red1[t] = s; red2[t] = ss;
        __syncthreads();
        for (int off = 128; off > 0; off >>= 1) {
            if (t < off) { red1[t] += red1[t + off]; red2[t] += red2[t + off]; }
            __syncthreads();
        }
        float mu   = red1[0] * (1.0f / DIM);
        float var  = red2[0] * (1.0f / DIM) - mu * mu;
        float rstd = rsqrtf(var + 1e-5f);
        float4 gv = *((const float4*)(g + t * 4));
        float4 bv = *((const float4*)(b + t * 4));
        ushort4 o;
        o.x = f2b((v.x - mu) * rstd * gv.x + bv.x);
        o.y = f2b((v.y - mu) * rstd * gv.y + bv.y);
        o.z = f2b((v.z - mu) * rstd * gv.z + bv.z);
        o.w = f2b((v.w - mu) * rstd * gv.w + bv.w);
        *((ushort4*)(lnout + tidx(row, t * 4, DIM))) = o;
    } else {
        int tt = bid - ROWS;
        const float* W; unsigned short* Wt; int K, N, bx, by;
        if (tt < 768) {
            W = qkv_w; Wt = wT_qkv; K = DIM; N = 3 * DIM; bx = tt % 48; by = tt / 48;
        } else if (tt < 768 + 256) {
            tt -= 768;
            W = proj_w; Wt = wT_proj; K = DIM; N = DIM; bx = tt % 16; by = tt / 16;
        } else if (tt < 768 + 256 + 1024) {
            tt -= 768 + 256;
            W = fc1_w; Wt = wT_fc1; K = DIM; N = HIDDEN; bx = tt % 64; by = tt / 64;
        } else {
            tt -= 768 + 256 + 1024;
            W = fc2_w; Wt = wT_fc2; K = HIDDEN; N = DIM; bx = tt % 16; by = tt / 16;
        }
        int n0 = bx * 64, k0 = by * 64;
        int cr = t >> 4;
        int cc = (t & 15) * 4;
        #pragma unroll
        for (int r = 0; r < 4; ++r) {
            int kk = cr + 16 * r;
            float4 v = *((const float4*)(W + (size_t)(k0 + kk) * N + n0 + cc));
            T[cc + 0][kk] = f2b(v.x);
            T[cc + 1][kk] = f2b(v.y);
            T[cc + 2][kk] = f2b(v.z);
            T[cc + 3][kk] = f2b(v.w);
        }
        __syncthreads();
        {
            int nn = t >> 2;
            int kg = (t & 3) * 16;
            #pragma unroll
            for (int p = 0; p < 2; ++p) {
                int k8 = kg + p * 8;
                ushort4 lo = *((ushort4*)&T[nn][k8]);
                ushort4 hi = *((ushort4*)&T[nn][k8 + 4]);
                unsigned short* dst = Wt + tidx(n0 + nn, k0 + k8, K);
                *((ushort4*)dst)       = lo;
                *((ushort4*)(dst + 4)) = hi;
            }
        }
    }
}

// -------- Fused: x1 = x + proj_b + p0 + p1 (fp32 -> xout), then LN -> tiled bf16 --------
__global__ __launch_bounds__(256) void reduce_ln(const unsigned short* __restrict__ p0,
                                                 const unsigned short* __restrict__ p1,
                                                 const float* __restrict__ x,
                                                 const float* __restrict__ bias,
                                                 const float* __restrict__ g,
                                                 const float* __restrict__ b,
                                                 float* __restrict__ xout,
                                                 unsigned short* __restrict__ lnout) {
    int row = blockIdx.x;
    int t = threadIdx.x;
    size_t i = (size_t)row * DIM + t * 4;
    float4 xv = *((const float4*)(x + i));
    float4 bi = *((const float4*)(bias + t * 4));
    uint2 w0 = *((const uint2*)(p0 + i));
    uint2 w1 = *((const uint2*)(p1 + i));
    float4 v;
    v.x = xv.x + bi.x + blo(w0.x) + blo(w1.x);
    v.y = xv.y + bi.y + bhi(w0.x) + bhi(w1.x);
    v.z = xv.z + bi.z + blo(w0.y) + blo(w1.y);
    v.w = xv.w + bi.w + bhi(w0.y) + bhi(w1.y);
    *((float4*)(xout + i)) = v;

    float s  = v.x + v.y + v.z + v.w;
    float ss = v.x * v.x + v.y * v.y + v.z * v.z + v.w * v.w;
    __shared__ float red1[256], red2[256];
    red1[t] = s; red2[t] = ss;
    __syncthreads();
    for (int off = 128; off > 0; off >>= 1) {
        if (t < off) { red1[t] += red1[t + off]; red2[t] += red2[t + off]; }
        __syncthreads();
    }
    float mu   = red1[0] * (1.0f / DIM);
    float var  = red2[0] * (1.0f / DIM) - mu * mu;
    float rstd = rsqrtf(var + 1e-5f);
    float4 gv = *((const float4*)(g + t * 4));
    float4 bv = *((const float4*)(b + t * 4));
    ushort4 o;
    o.x = f2b((v.x - mu) * rstd * gv.x + bv.x);
    o.y = f2b((v.y - mu) * rstd * gv.y + bv.y);
    o.z = f2b((v.z - mu) * rstd * gv.z + bv.z);
    o.w = f2b((v.w - mu) * rstd * gv.w + bv.w);
    *((ushort4*)(lnout + tidx(row, t * 4, DIM))) = o;
}

// ---------------- 128x64-tile MFMA GEMM (R3 loop structure, 2x grid for residency) ----------------
// 4 waves as 2x2; wave tile 64x32 (acc[4][2]). LDS 24KB (A 16 + B 8) -> 6 blocks/CU.
// Per K-step: stage 6 chunks/wave, sync, 16 MFMA x 2kc, sync.
// fuse: 0 = bias, bf16 TILED out (+V scatter); 1 = bias+GELU tiled; 3 = split-K bf16 row-major.
__global__ __launch_bounds__(256, 6) void mfma_gemm(const unsigned short* __restrict__ A,
                                                 const unsigned short* __restrict__ Bt,
                                                 const float* __restrict__ bias,
                                                 void* __restrict__ Cout,
                                                 unsigned short* __restrict__ vt,
                                                 unsigned short* __restrict__ p0,
                                                 unsigned short* __restrict__ p1,
                                                 unsigned short* __restrict__ p2,
                                                 unsigned short* __restrict__ p3,
                                                 int M, int N, int K, int Ksplit, int fuse) {
    __shared__ __align__(16) short Asm[8192];   // 16 chunks: [mb8][kc2]
    __shared__ __align__(16) short Bsm[4096];   // 8 chunks:  [nb4][kc2]

    const int tid  = threadIdx.x;
    const int lane = tid & 63;
    const int wave = tid >> 6;
    const int wy = wave >> 1, wx = wave & 1;
    const int lr = lane & 15;
    const int lq = lane >> 4;

    // XCD-L2 supergroup remap (groups of 8 n-tiles, m fastest within group)
    int m_t, n_t;
    {
        const int mt = gridDim.x, ntl = gridDim.y, G = 8;
        if (ntl > G) {
            int lin = blockIdx.y * mt + blockIdx.x;
            int gsz = mt * G;
            int grp = lin / gsz;
            int rem = lin - grp * gsz;
            m_t = rem % mt;
            n_t = grp * G + rem / mt;
        } else { m_t = blockIdx.x; n_t = blockIdx.y; }
    }
    const int m0 = m_t * 128, n0 = n_t * 64;
    const int kbase = blockIdx.z * Ksplit;
    const int kch = K >> 5;

    f32x4 acc[4][2];
    #pragma unroll
    for (int i = 0; i < 4; ++i)
        #pragma unroll
        for (int j = 0; j < 2; ++j)
            acc[i][j] = (f32x4){0.f, 0.f, 0.f, 0.f};

    // staging: wave stages A chunks {wave*4+j, j<4}, B chunks {wave*2+j, j<2}
    const unsigned short* ag[4]; const unsigned short* bg[2];
    #pragma unroll
    for (int j = 0; j < 4; ++j) {
        int cid = wave * 4 + j;
        ag[j] = A + ((size_t)((m0 >> 4) + (cid >> 1)) * kch + (kbase >> 5) + (cid & 1)) * 512 + lane * 8;
    }
    #pragma unroll
    for (int j = 0; j < 2; ++j) {
        int cid = wave * 2 + j;
        bg[j] = Bt + ((size_t)((n0 >> 4) + (cid >> 1)) * kch + (kbase >> 5) + (cid & 1)) * 512 + lane * 8;
    }

    for (int k0 = 0; k0 < Ksplit; k0 += 64) {
        #pragma unroll
        for (int j = 0; j < 4; ++j) {
            gload_lds16(ag[j], &Asm[(wave * 4 + j) * 512]);
            ag[j] += 1024;
        }
        #pragma unroll
        for (int j = 0; j < 2; ++j) {
            gload_lds16(bg[j], &Bsm[(wave * 2 + j) * 512]);
            bg[j] += 1024;
        }
        __syncthreads();
        #pragma unroll
        for (int kc = 0; kc < 2; ++kc) {
            s16x8 af[4], bf[2];
            #pragma unroll
            for (int i = 0; i < 4; ++i)
                af[i] = *((const s16x8*)&Asm[((wy * 4 + i) * 2 + kc) * 512 + lane * 8]);
            #pragma unroll
            for (int j = 0; j < 2; ++j)
                bf[j] = *((const s16x8*)&Bsm[((wx * 2 + j) * 2 + kc) * 512 + lane * 8]);
            #pragma unroll
            for (int i = 0; i < 4; ++i)
                #pragma unroll
                for (int j = 0; j < 2; ++j)
                    acc[i][j] = __builtin_amdgcn_mfma_f32_16x16x32_bf16(af[i], bf[j], acc[i][j], 0, 0, 0);
        }
        __syncthreads();
    }

    // ======================= epilogue =======================
    // LDS dead after final barrier; wave-private 4KB (2048 shorts) each.
    short* Wl = (wave < 2 ? Asm : Bsm) + (wave & 1) * 2048;

    if (fuse == 0 && vt && (n0 + wx * 32) >= 2 * DIM) {
        // V-scatter path (QKV only; wave-uniform): scalar stores (special layout)
        #pragma unroll
        for (int j = 0; j < 2; ++j) {
            int col = n0 + wx * 32 + j * 16 + lr;
            float bi = bias[col];
            #pragma unroll
            for (int i = 0; i < 4; ++i) {
                int row0 = m0 + wy * 64 + i * 16 + lq * 4;
                #pragma unroll
                for (int r = 0; r < 4; ++r) {
                    float val = acc[i][j][r] + bi;
                    int row = row0 + r;
                    int b_ = row >> 10, tok = row & 1023;
                    int hd = col - 2 * DIM, h_ = hd >> 6, d = hd & 63;
                    size_t o = (size_t)(b_ * 16 + h_) * 65536
                             + ((size_t)(d >> 4) * 32 + (tok >> 5)) * 512
                             + ((tok & 31) >> 3) * 128 + (d & 15) * 8 + (tok & 7);
                    vt[o] = f2b(val);
                }
            }
        }
    } else if (fuse == 3) {
        // row-major partials: stage wave 64x32 in LDS (col ^= (rowL&3)<<3), b128 out
        #pragma unroll
        for (int j = 0; j < 2; ++j) {
            #pragma unroll
            for (int i = 0; i < 4; ++i) {
                #pragma unroll
                for (int r = 0; r < 4; ++r) {
                    int rowL = i * 16 + lq * 4 + r;
                    int colL = (j * 16 + lr) ^ ((rowL & 3) << 3);
                    Wl[rowL * 32 + colL] = (short)f2b(acc[i][j][r]);
                }
            }
        }
        int z = blockIdx.z;
        unsigned short* P = (z == 0) ? p0 : (z == 1) ? p1 : (z == 2) ? p2 : p3;
        unsigned short* Prow = P + (size_t)(m0 + wy * 64 + lane) * N + n0 + wx * 32;
        #pragma unroll
        for (int c = 0; c < 4; ++c) {
            int colr = (c * 8) ^ ((lane & 3) << 3);
            s16x8 v = *((const s16x8*)&Wl[lane * 32 + colr]);
            *((s16x8*)&Prow[c * 8]) = v;
        }
    } else {
        // tiled bf16 out (fuse 0 Q/K region, fuse 1): stage 4 chunks x 512, b128 out
        #pragma unroll
        for (int j = 0; j < 2; ++j) {
            float bi = bias[n0 + wx * 32 + j * 16 + lr];
            #pragma unroll
            for (int i = 0; i < 4; ++i) {
                #pragma unroll
                for (int r = 0; r < 4; ++r) {
                    float val = acc[i][j][r] + bi;
                    if (fuse == 1) val = gelu_f(val);
                    int hi = j * 2 + (lr >> 3);
                    int pos = hi * 128 + (lq * 4 + r) * 8 + (lr & 7);
                    pos ^= ((pos >> 7) & 3) << 3;
                    Wl[i * 512 + pos] = (short)f2b(val);
                }
            }
        }
        const size_t rc0 = (size_t)((m0 + wy * 64) >> 4);
        const size_t cc0 = (size_t)((n0 + wx * 32) >> 5);
        const size_t nch = (size_t)(N >> 5);
        #pragma unroll
        for (int c = 0; c < 4; ++c) {
            int raddr = lane * 8;
            raddr ^= ((raddr >> 7) & 3) << 3;
            s16x8 v = *((const s16x8*)&Wl[c * 512 + raddr]);
            size_t chunk = (rc0 + c) * nch + cc0;
            *((s16x8*)&((unsigned short*)Cout)[chunk * 512 + lane * 8]) = v;
        }
    }
}

// ---------- Split-K reduce (FC2): out = x + bias + sum_s partial_s ----------
__global__ __launch_bounds__(256) void reduce_kernel(const unsigned short* __restrict__ p0,
                                                     const unsigned short* __restrict__ p1,
                                                     const unsigned short* __restrict__ p2,
                                                     const unsigned short* __restrict__ p3,
                                                     int S,
                                                     const float* __restrict__ x,
                                                     const float* __restrict__ bias,
                                                     float* __restrict__ out) {
    int i = (blockIdx.x * 256 + threadIdx.x) * 8;
    int col = i & (DIM - 1);
    float4 b0 = *((const float4*)(bias + col));
    float4 b1 = *((const float4*)(bias + col + 4));
    float4 x0 = *((const float4*)(x + i));
    float4 x1 = *((const float4*)(x + i + 4));
    float a[8] = {x0.x + b0.x, x0.y + b0.y, x0.z + b0.z, x0.w + b0.w,
                  x1.x + b1.x, x1.y + b1.y, x1.z + b1.z, x1.w + b1.w};
    const unsigned short* ps[4] = {p0, p1, p2, p3};
    for (int s = 0; s < S; ++s) {
        uint4 w = *((const uint4*)(ps[s] + i));
        a[0] += blo(w.x); a[1] += bhi(w.x);
        a[2] += blo(w.y); a[3] += bhi(w.y);
        a[4] += blo(w.z); a[5] += bhi(w.z);
        a[6] += blo(w.w); a[7] += bhi(w.w);
    }
    *((float4*)(out + i))     = make_float4(a[0], a[1], a[2], a[3]);
    *((float4*)(out + i + 4)) = make_float4(a[4], a[5], a[6], a[7]);
}

// ------------- MFMA flash attention, no-max softmax + ones-column row sums -------------
__global__ __launch_bounds__(256) void fattn_mfma(const unsigned short* __restrict__ qkv,
                                                  const unsigned short* __restrict__ Vt,
                                                  unsigned short* __restrict__ out) {
    __shared__ __align__(16) short Qs[8192];
    __shared__ __align__(16) short Ks[4096];
    __shared__ __align__(16) short Vs[4096];
    __shared__ __align__(16) short Ps[128 * 72];
    __shared__ __align__(16) short OnesB[512];   // B-frag: col0 = 1.0, rest 0

    const int tid = threadIdx.x, lane = tid & 63, wave = tid >> 6;
    const int lr = lane & 15, lq = lane >> 4;
    const int L = blockIdx.x;
    const int bh = (L & 7) + 8 * (L >> 6);
    const int b = bh >> 4, h = bh & 15;
    const int q0 = ((L >> 3) & 7) * 128;

    {
        s16x8 z = (s16x8){0,0,0,0,0,0,0,0};
        if (lr == 0) { z[0] = (short)0x3F80; z[1] = (short)0x3F80;
                       z[2] = (short)0x3F80; z[3] = (short)0x3F80;
                       z[4] = (short)0x3F80; z[5] = (short)0x3F80;
                       z[6] = (short)0x3F80; z[7] = (short)0x3F80; }
        if (wave == 0) *((s16x8*)&OnesB[lane * 8]) = z;
    }

    #pragma unroll
    for (int j = 0; j < 4; ++j) {
        int cid = wave * 4 + j;
        const unsigned short* g = qkv + ((size_t)(((b * SEQ + q0) >> 4) + (cid >> 1)) * 96
                                         + 2 * h + (cid & 1)) * 512 + lane * 8;
        gload_lds16(g, &Qs[cid * 512]);
    }

    const unsigned short* kg_[2]; const unsigned short* vg_[2];
    short *kl_[2], *vl_[2];
    #pragma unroll
    for (int j = 0; j < 2; ++j) {
        int cid = wave * 2 + j;
        kg_[j] = qkv + ((size_t)(((b * SEQ) >> 4) + (cid >> 1)) * 96
                        + 32 + 2 * h + (cid & 1)) * 512 + lane * 8;
        vg_[j] = Vt + (size_t)bh * 65536
                 + ((size_t)(cid >> 1) * 32 + (cid & 1)) * 512 + lane * 8;
        kl_[j] = &Ks[cid * 512];
        vl_[j] = &Vs[cid * 512];
    }

    f32x4 osum[2][5];
    #pragma unroll
    for (int i = 0; i < 2; ++i)
        #pragma unroll
        for (int d = 0; d < 5; ++d)
            osum[i][d] = (f32x4){0.f, 0.f, 0.f, 0.f};

    const float c = 0.125f * 1.44269504f;   // scale * log2(e)

    for (int k0 = 0; k0 < SEQ; k0 += 64) {
        #pragma unroll
        for (int j = 0; j < 2; ++j) {
            gload_lds16(kg_[j], kl_[j]);
            gload_lds16(vg_[j], vl_[j]);
            kg_[j] += 4 * 96 * 512;
            vg_[j] += 1024;
        }
        __syncthreads();

        f32x4 s[2][4];
        #pragma unroll
        for (int i = 0; i < 2; ++i)
            #pragma unroll
            for (int jb = 0; jb < 4; ++jb)
                s[i][jb] = (f32x4){0.f, 0.f, 0.f, 0.f};
        #pragma unroll
        for (int kc = 0; kc < 2; ++kc) {
            s16x8 aq0 = *((const s16x8*)&Qs[(wave * 4 + 0 + kc) * 512 + lane * 8]);
            s16x8 aq1 = *((const s16x8*)&Qs[(wave * 4 + 2 + kc) * 512 + lane * 8]);
            #pragma unroll
            for (int jb = 0; jb < 4; ++jb) {
                s16x8 bk = *((const s16x8*)&Ks[(jb * 2 + kc) * 512 + lane * 8]);
                s[0][jb] = __builtin_amdgcn_mfma_f32_16x16x32_bf16(aq0, bk, s[0][jb], 0, 0, 0);
                s[1][jb] = __builtin_amdgcn_mfma_f32_16x16x32_bf16(aq1, bk, s[1][jb], 0, 0, 0);
            }
        }

        #pragma unroll
        for (int i = 0; i < 2; ++i)
            #pragma unroll
            for (int r = 0; r < 4; ++r) {
                int prow = (wave * 2 + i) * 16 + lq * 4 + r;
                #pragma unroll
                for (int jb = 0; jb < 4; ++jb)
                    Ps[prow * 72 + jb * 16 + lr] = (short)f2b(exp2f(s[i][jb][r] * c));
            }

        #pragma unroll
        for (int kc = 0; kc < 2; ++kc) {
            s16x8 ap0 = *((const s16x8*)&Ps[((wave * 2 + 0) * 16 + lr) * 72 + kc * 32 + lq * 8]);
            s16x8 ap1 = *((const s16x8*)&Ps[((wave * 2 + 1) * 16 + lr) * 72 + kc * 32 + lq * 8]);
            #pragma unroll
            for (int db = 0; db < 4; ++db) {
                s16x8 bv = *((const s16x8*)&Vs[(db * 2 + kc) * 512 + lane * 8]);
                osum[0][db] = __builtin_amdgcn_mfma_f32_16x16x32_bf16(ap0, bv, osum[0][db], 0, 0, 0);
                osum[1][db] = __builtin_amdgcn_mfma_f32_16x16x32_bf16(ap1, bv, osum[1][db], 0, 0, 0);
            }
            s16x8 bo = *((const s16x8*)&OnesB[lane * 8]);
            osum[0][4] = __builtin_amdgcn_mfma_f32_16x16x32_bf16(ap0, bo, osum[0][4], 0, 0, 0);
            osum[1][4] = __builtin_amdgcn_mfma_f32_16x16x32_bf16(ap1, bo, osum[1][4], 0, 0, 0);
        }
        __syncthreads();
    }

    #pragma unroll
    for (int i = 0; i < 2; ++i) {
        int qrow = q0 + (wave * 2 + i) * 16 + lq * 4;
        #pragma unroll
        for (int r = 0; r < 4; ++r) {
            float lsum = __shfl(osum[i][4][r], lane & 48, 64);
            float inv = 1.0f / lsum;
            int row = b * SEQ + qrow + r;
            #pragma unroll
            for (int db = 0; db < 4; ++db)
                out[tidx(row, h * 64 + db * 16 + lr, DIM)] = f2b(osum[i][db][r] * inv);
        }
    }
}

extern "C" void kernel_launch(void* const* d_in, const int* in_sizes, int n_in,
                              void* d_out, int out_size, void* d_ws, size_t ws_size,
                              hipStream_t stream) {
    const float* x      = (const float*)d_in[0];
    const float* ln1_g  = (const float*)d_in[1];
    const float* ln1_b  = (const float*)d_in[2];
    const float* ln2_g  = (const float*)d_in[3];
    const float* ln2_b  = (const float*)d_in[4];
    const float* qkv_w  = (const float*)d_in[5];
    const float* qkv_b  = (const float*)d_in[6];
    const float* proj_w = (const float*)d_in[7];
    const float* proj_b = (const float*)d_in[8];
    const float* fc1_w  = (const float*)d_in[9];
    const float* fc1_b  = (const float*)d_in[10];
    const float* fc2_w  = (const float*)d_in[11];
    const float* fc2_b  = (const float*)d_in[12];
    float* out = (float*)d_out;

    // workspace layout (MiB), 72 total — liveness-packed
    char* ws = (char*)d_ws;
    unsigned short* wT_fc2  = (unsigned short*)(ws);
    unsigned short* wT_qkv  = (unsigned short*)(ws + (8u  << 20));
    unsigned short* wT_proj = (unsigned short*)(ws + (14u << 20));
    unsigned short* qkvbuf  = (unsigned short*)(ws + (16u << 20));
    unsigned short* Vt      = (unsigned short*)(ws + (40u << 20));
    unsigned short* attnout = (unsigned short*)(ws + (48u << 20));
    unsigned short* lnout   = (unsigned short*)(ws + (56u << 20));
    unsigned short* wT_fc1  = (unsigned short*)(ws + (64u << 20));
    unsigned short* gelu    = (unsigned short*)(ws + (16u << 20));
    unsigned short* pp0 = (unsigned short*)(ws + (16u << 20));
    unsigned short* pp1 = (unsigned short*)(ws + (24u << 20));
    unsigned short* fp0 = (unsigned short*)(ws + (48u << 20));
    unsigned short* fp1 = (unsigned short*)(ws + (56u << 20));
    unsigned short* fp2 = (unsigned short*)(ws + (64u << 20));
    unsigned short* fp3 = (unsigned short*)(ws + (8u  << 20));

    // 0+1) prep: LN1(x) -> lnout tiled  AND  all 4 weight converts (one launch)
    prep_kernel<<<ROWS + 3072, 256, 0, stream>>>(
        x, ln1_g, ln1_b, lnout,
        qkv_w, wT_qkv, proj_w, wT_proj, fc1_w, wT_fc1, fc2_w, wT_fc2);
    // 2) qkv = h1 @ qkv_w + qkv_b -> Q,K tiled; V -> Vt tiled (fused transpose)
    mfma_gemm<<<dim3(ROWS / 128, 3 * DIM / 64, 1), 256, 0, stream>>>(
        lnout, wT_qkv, qkv_b, qkvbuf, Vt, nullptr, nullptr, nullptr, nullptr,
        ROWS, 3 * DIM, DIM, DIM, 0);
    // 3) o = mfma flash attention -> attnout tiled
    fattn_mfma<<<(SEQ / 128) * BATCH * HEADS, 256, 0, stream>>>(qkvbuf, Vt, attnout);
    // 4) proj split-K (S=2): partials = o @ proj_w (plain bf16)
    mfma_gemm<<<dim3(ROWS / 128, DIM / 64, 2), 256, 0, stream>>>(
        attnout, wT_proj, proj_b, nullptr, nullptr, pp0, pp1, nullptr, nullptr,
        ROWS, DIM, DIM, DIM / 2, 3);
    // 4b+5) x1 = x + sum + proj_b -> d_out; h2 = LN2(x1) -> lnout tiled  (FUSED)
    reduce_ln<<<ROWS, 256, 0, stream>>>(pp0, pp1, x, proj_b, ln2_g, ln2_b, out, lnout);
    // 6) g = gelu(h2 @ fc1_w + fc1_b) -> bf16 tiled  [4096 x 4096]
    mfma_gemm<<<dim3(ROWS / 128, HIDDEN / 64, 1), 256, 0, stream>>>(
        lnout, wT_fc1, fc1_b, gelu, nullptr, nullptr, nullptr, nullptr, nullptr,
        ROWS, HIDDEN, DIM, DIM, 1);
    // 7) FC2 split-K (S=4): partials = g @ fc2_w (plain bf16)
    mfma_gemm<<<dim3(ROWS / 128, DIM / 64, 4), 256, 0, stream>>>(
        gelu, wT_fc2, fc2_b, nullptr, nullptr, fp0, fp1, fp2, fp3,
        ROWS, DIM, HIDDEN, HIDDEN / 4, 3);
    // 7b) out = x1 + sum(partials) + fc2_b -> d_out (fp32, in-place residual)
    reduce_kernel<<<ROWS * DIM / 2048, 256, 0, stream>>>(
        fp0, fp1, fp2, fp3, 4, out, fc2_b, out);
}

// Round 6
// 319.345 us; speedup vs baseline: 1.1471x; 1.0754x over previous
//
#include <hip/hip_runtime.h>
#include <math.h>

#define DIM    1024
#define HEADS  16
#define HDIM   64
#define HIDDEN 4096
#define BATCH  4
#define SEQ    1024
#define ROWS   (BATCH * SEQ)   // 4096

typedef short s16x8 __attribute__((ext_vector_type(8)));
typedef float f32x4 __attribute__((ext_vector_type(4)));

// ---- bf16 helpers ----
__device__ __forceinline__ float blo(unsigned int u) {
    union { unsigned int i; float f; } x; x.i = u << 16; return x.f;
}
__device__ __forceinline__ float bhi(unsigned int u) {
    union { unsigned int i; float f; } x; x.i = u & 0xffff0000u; return x.f;
}
__device__ __forceinline__ unsigned short f2b(float f) {   // round-to-nearest-even
    union { float f; unsigned int i; } x; x.f = f;
    unsigned int r = x.i + 0x7fffu + ((x.i >> 16) & 1u);
    return (unsigned short)(r >> 16);
}

// ---- fast exact-GELU: branchless A&S 7.1.26 erf, max |err| ~1.5e-7 ----
__device__ __forceinline__ float gelu_f(float x) {
    float z  = fabsf(x) * 0.70710678118f;
    float t  = __builtin_amdgcn_rcpf(__builtin_fmaf(0.3275911f, z, 1.0f));
    float p  = ((((1.061405429f * t - 1.453152027f) * t + 1.421413741f) * t
                 - 0.284496736f) * t + 0.254829592f) * t;
    float e  = exp2f(-0.72134752f * x * x);       // exp(-z^2), z^2 = x^2/2
    float w  = 0.5f * p * e;                      // 0.5*(1 - erf(|z|))
    float phi = (x >= 0.0f) ? (1.0f - w) : w;     // Phi(x) = 0.5*(1+erf(z))
    return x * phi;
}

// ---- TILED operand layout: chunk = 16 rows x 32 k, 1KB contiguous, MFMA lane order ----
__device__ __forceinline__ size_t tidx(int row, int k, int Kdim) {
    return ((size_t)(row >> 4) * (Kdim >> 5) + (k >> 5)) * 512
         + (size_t)(((k & 31) >> 3) * 128 + (row & 15) * 8 + (k & 7));
}

// ---- async global->LDS, 16B/lane ----
__device__ __forceinline__ void gload_lds16(const void* g, void* l) {
    __builtin_amdgcn_global_load_lds(
        (const __attribute__((address_space(1))) unsigned int*)g,
        (__attribute__((address_space(3))) unsigned int*)l, 16, 0, 0);
}

// ---------------- prep: LN1 rows + all 4 weight convert/transpose, ONE launch ----------------
__global__ __launch_bounds__(256) void prep_kernel(const float* __restrict__ x,
                                                   const float* __restrict__ g,
                                                   const float* __restrict__ b,
                                                   unsigned short* __restrict__ lnout,
                                                   const float* __restrict__ qkv_w,
                                                   unsigned short* __restrict__ wT_qkv,
                                                   const float* __restrict__ proj_w,
                                                   unsigned short* __restrict__ wT_proj,
                                                   const float* __restrict__ fc1_w,
                                                   unsigned short* __restrict__ wT_fc1,
                                                   const float* __restrict__ fc2_w,
                                                   unsigned short* __restrict__ wT_fc2) {
    __shared__ float red1[256], red2[256];
    __shared__ unsigned short T[64][68];
    const int bid = blockIdx.x;
    const int t = threadIdx.x;

    if (bid < ROWS) {
        int row = bid;
        const float* xr = x + (size_t)row * DIM;
        float4 v = *((const float4*)(xr + t * 4));
        float s  = v.x + v.y + v.z + v.w;
        float ss = v.x * v.x + v.y * v.y + v.z * v.z + v.w * v.w;
        red1[t] = s; red2[t] = ss;
        __syncthreads();
        for (int off = 128; off > 0; off >>= 1) {
            if (t < off) { red1[t] += red1[t + off]; red2[t] += red2[t + off]; }
            __syncthreads();
        }
        float mu   = red1[0] * (1.0f / DIM);
        float var  = red2[0] * (1.0f / DIM) - mu * mu;
        float rstd = rsqrtf(var + 1e-5f);
        float4 gv = *((const float4*)(g + t * 4));
        float4 bv = *((const float4*)(b + t * 4));
        ushort4 o;
        o.x = f2b((v.x - mu) * rstd * gv.x + bv.x);
        o.y = f2b((v.y - mu) * rstd * gv.y + bv.y);
        o.z = f2b((v.z - mu) * rstd * gv.z + bv.z);
        o.w = f2b((v.w - mu) * rstd * gv.w + bv.w);
        *((ushort4*)(lnout + tidx(row, t * 4, DIM))) = o;
    } else {
        int tt = bid - ROWS;
        const float* W; unsigned short* Wt; int K, N, bx, by;
        if (tt < 768) {
            W = qkv_w; Wt = wT_qkv; K = DIM; N = 3 * DIM; bx = tt % 48; by = tt / 48;
        } else if (tt < 768 + 256) {
            tt -= 768;
            W = proj_w; Wt = wT_proj; K = DIM; N = DIM; bx = tt % 16; by = tt / 16;
        } else if (tt < 768 + 256 + 1024) {
            tt -= 768 + 256;
            W = fc1_w; Wt = wT_fc1; K = DIM; N = HIDDEN; bx = tt % 64; by = tt / 64;
        } else {
            tt -= 768 + 256 + 1024;
            W = fc2_w; Wt = wT_fc2; K = HIDDEN; N = DIM; bx = tt % 16; by = tt / 16;
        }
        int n0 = bx * 64, k0 = by * 64;
        int cr = t >> 4;
        int cc = (t & 15) * 4;
        #pragma unroll
        for (int r = 0; r < 4; ++r) {
            int kk = cr + 16 * r;
            float4 v = *((const float4*)(W + (size_t)(k0 + kk) * N + n0 + cc));
            T[cc + 0][kk] = f2b(v.x);
            T[cc + 1][kk] = f2b(v.y);
            T[cc + 2][kk] = f2b(v.z);
            T[cc + 3][kk] = f2b(v.w);
        }
        __syncthreads();
        {
            int nn = t >> 2;
            int kg = (t & 3) * 16;
            #pragma unroll
            for (int p = 0; p < 2; ++p) {
                int k8 = kg + p * 8;
                ushort4 lo = *((ushort4*)&T[nn][k8]);
                ushort4 hi = *((ushort4*)&T[nn][k8 + 4]);
                unsigned short* dst = Wt + tidx(n0 + nn, k0 + k8, K);
                *((ushort4*)dst)       = lo;
                *((ushort4*)(dst + 4)) = hi;
            }
        }
    }
}

// -------- Fused: x1 = x + proj_b + p0 + p1 (fp32 -> xout), then LN -> tiled bf16 --------
__global__ __launch_bounds__(256) void reduce_ln(const unsigned short* __restrict__ p0,
                                                 const unsigned short* __restrict__ p1,
                                                 const float* __restrict__ x,
                                                 const float* __restrict__ bias,
                                                 const float* __restrict__ g,
                                                 const float* __restrict__ b,
                                                 float* __restrict__ xout,
                                                 unsigned short* __restrict__ lnout) {
    int row = blockIdx.x;
    int t = threadIdx.x;
    size_t i = (size_t)row * DIM + t * 4;
    float4 xv = *((const float4*)(x + i));
    float4 bi = *((const float4*)(bias + t * 4));
    uint2 w0 = *((const uint2*)(p0 + i));
    uint2 w1 = *((const uint2*)(p1 + i));
    float4 v;
    v.x = xv.x + bi.x + blo(w0.x) + blo(w1.x);
    v.y = xv.y + bi.y + bhi(w0.x) + bhi(w1.x);
    v.z = xv.z + bi.z + blo(w0.y) + blo(w1.y);
    v.w = xv.w + bi.w + bhi(w0.y) + bhi(w1.y);
    *((float4*)(xout + i)) = v;

    float s  = v.x + v.y + v.z + v.w;
    float ss = v.x * v.x + v.y * v.y + v.z * v.z + v.w * v.w;
    __shared__ float red1[256], red2[256];
    red1[t] = s; red2[t] = ss;
    __syncthreads();
    for (int off = 128; off > 0; off >>= 1) {
        if (t < off) { red1[t] += red1[t + off]; red2[t] += red2[t + off]; }
        __syncthreads();
    }
    float mu   = red1[0] * (1.0f / DIM);
    float var  = red2[0] * (1.0f / DIM) - mu * mu;
    float rstd = rsqrtf(var + 1e-5f);
    float4 gv = *((const float4*)(g + t * 4));
    float4 bv = *((const float4*)(b + t * 4));
    ushort4 o;
    o.x = f2b((v.x - mu) * rstd * gv.x + bv.x);
    o.y = f2b((v.y - mu) * rstd * gv.y + bv.y);
    o.z = f2b((v.z - mu) * rstd * gv.z + bv.z);
    o.w = f2b((v.w - mu) * rstd * gv.w + bv.w);
    *((ushort4*)(lnout + tidx(row, t * 4, DIM))) = o;
}

// ---------------- 128-tile MFMA GEMM (R3 proven config) ----------------
// fuse: 0 = bias, bf16 TILED out (V-cols >= 2*DIM scatter to vt); 1 = bias+GELU tiled out;
//       3 = split-K partial, plain bf16 row-major -> p{z}
__global__ __launch_bounds__(256, 4) void mfma_gemm(const unsigned short* __restrict__ A,
                                                 const unsigned short* __restrict__ Bt,
                                                 const float* __restrict__ bias,
                                                 void* __restrict__ Cout,
                                                 unsigned short* __restrict__ vt,
                                                 unsigned short* __restrict__ p0,
                                                 unsigned short* __restrict__ p1,
                                                 unsigned short* __restrict__ p2,
                                                 unsigned short* __restrict__ p3,
                                                 int M, int N, int K, int Ksplit, int fuse) {
    __shared__ __align__(16) short Asm[8192];
    __shared__ __align__(16) short Bsm[8192];

    const int tid  = threadIdx.x;
    const int lane = tid & 63;
    const int wave = tid >> 6;
    const int wy = wave >> 1, wx = wave & 1;
    const int lr = lane & 15;
    const int lq = lane >> 4;

    // XCD-L2 supergroup remap (groups of 8 n-tiles, m fastest within group)
    int m_t, n_t;
    {
        const int mt = gridDim.x, ntl = gridDim.y, G = 8;
        if (ntl > G) {
            int lin = blockIdx.y * mt + blockIdx.x;
            int gsz = mt * G;
            int grp = lin / gsz;
            int rem = lin - grp * gsz;
            m_t = rem % mt;
            n_t = grp * G + rem / mt;
        } else { m_t = blockIdx.x; n_t = blockIdx.y; }
    }
    const int m0 = m_t * 128, n0 = n_t * 128;
    const int kbase = blockIdx.z * Ksplit;
    const int kch = K >> 5;

    f32x4 acc[4][4];
    #pragma unroll
    for (int i = 0; i < 4; ++i)
        #pragma unroll
        for (int j = 0; j < 4; ++j)
            acc[i][j] = (f32x4){0.f, 0.f, 0.f, 0.f};

    const unsigned short* ag[4]; const unsigned short* bg[4];
    short* al[4]; short* bl[4];
    #pragma unroll
    for (int j = 0; j < 4; ++j) {
        int cid = wave * 4 + j;
        int mb  = cid >> 1;
        int kc  = cid & 1;
        ag[j] = A  + ((size_t)((m0 >> 4) + mb) * kch + (kbase >> 5) + kc) * 512 + lane * 8;
        bg[j] = Bt + ((size_t)((n0 >> 4) + mb) * kch + (kbase >> 5) + kc) * 512 + lane * 8;
        al[j] = &Asm[cid * 512];
        bl[j] = &Bsm[cid * 512];
    }

    for (int k0 = 0; k0 < Ksplit; k0 += 64) {
        #pragma unroll
        for (int j = 0; j < 4; ++j) {
            gload_lds16(ag[j], al[j]);
            gload_lds16(bg[j], bl[j]);
            ag[j] += 1024; bg[j] += 1024;
        }
        __syncthreads();
        #pragma unroll
        for (int kc = 0; kc < 2; ++kc) {
            s16x8 af[4], bf[4];
            #pragma unroll
            for (int i = 0; i < 4; ++i)
                af[i] = *((const s16x8*)&Asm[((wy * 4 + i) * 2 + kc) * 512 + lane * 8]);
            #pragma unroll
            for (int j = 0; j < 4; ++j)
                bf[j] = *((const s16x8*)&Bsm[((wx * 4 + j) * 2 + kc) * 512 + lane * 8]);
            #pragma unroll
            for (int i = 0; i < 4; ++i)
                #pragma unroll
                for (int j = 0; j < 4; ++j)
                    acc[i][j] = __builtin_amdgcn_mfma_f32_16x16x32_bf16(af[i], bf[j], acc[i][j], 0, 0, 0);
        }
        __syncthreads();
    }

    // ======================= epilogue =======================
    // All LDS dead after final barrier; wave-private 8KB regions, no barriers needed.
    short* Wl = (wave < 2 ? Asm : Bsm) + (wave & 1) * 4096;

    if (fuse == 0 && vt && (n0 + wx * 64) >= 2 * DIM) {
        // V-scatter path (QKV only; wave-uniform): scalar stores (special layout)
        #pragma unroll
        for (int j = 0; j < 4; ++j) {
            int col = n0 + wx * 64 + j * 16 + lr;
            float bi = bias[col];
            #pragma unroll
            for (int i = 0; i < 4; ++i) {
                int row0 = m0 + wy * 64 + i * 16 + lq * 4;
                #pragma unroll
                for (int r = 0; r < 4; ++r) {
                    float val = acc[i][j][r] + bi;
                    int row = row0 + r;
                    int b_ = row >> 10, tok = row & 1023;
                    int hd = col - 2 * DIM, h_ = hd >> 6, d = hd & 63;
                    size_t o = (size_t)(b_ * 16 + h_) * 65536
                             + ((size_t)(d >> 4) * 32 + (tok >> 5)) * 512
                             + ((tok & 31) >> 3) * 128 + (d & 15) * 8 + (tok & 7);
                    vt[o] = f2b(val);
                }
            }
        }
    } else if (fuse == 3) {
        // row-major partials: stage [64][64] in LDS (col ^= (rowL&7)<<3), b128 out
        #pragma unroll
        for (int j = 0; j < 4; ++j) {
            #pragma unroll
            for (int i = 0; i < 4; ++i) {
                #pragma unroll
                for (int r = 0; r < 4; ++r) {
                    int rowL = i * 16 + lq * 4 + r;
                    int colL = (j * 16 + lr) ^ ((rowL & 7) << 3);
                    Wl[rowL * 64 + colL] = (short)f2b(acc[i][j][r]);
                }
            }
        }
        int z = blockIdx.z;
        unsigned short* P = (z == 0) ? p0 : (z == 1) ? p1 : (z == 2) ? p2 : p3;
        unsigned short* Prow = P + (size_t)(m0 + wy * 64 + lane) * N + n0 + wx * 64;
        #pragma unroll
        for (int c = 0; c < 8; ++c) {
            int colr = (c * 8) ^ ((lane & 7) << 3);
            s16x8 v = *((const s16x8*)&Wl[lane * 64 + colr]);
            *((s16x8*)&Prow[c * 8]) = v;
        }
    } else {
        // tiled bf16 out (fuse 0 Q/K region, fuse 1): stage 8 chunks x 512, b128 out
        #pragma unroll
        for (int j = 0; j < 4; ++j) {
            float bi = bias[n0 + wx * 64 + j * 16 + lr];
            #pragma unroll
            for (int i = 0; i < 4; ++i) {
                #pragma unroll
                for (int r = 0; r < 4; ++r) {
                    float val = acc[i][j][r] + bi;
                    if (fuse == 1) val = gelu_f(val);
                    int colL = (j & 1) * 16 + lr;
                    int hi = colL >> 3;
                    int pos = hi * 128 + (lq * 4 + r) * 8 + (lr & 7);
                    pos ^= ((pos >> 7) & 3) << 3;
                    Wl[(i * 2 + (j >> 1)) * 512 + pos] = (short)f2b(val);
                }
            }
        }
        const size_t rc0 = (size_t)((m0 + wy * 64) >> 4);
        const size_t cc0 = (size_t)((n0 + wx * 64) >> 5);
        const size_t nch = (size_t)(N >> 5);
        #pragma unroll
        for (int c = 0; c < 8; ++c) {
            int raddr = lane * 8;
            raddr ^= ((raddr >> 7) & 3) << 3;
            s16x8 v = *((const s16x8*)&Wl[c * 512 + raddr]);
            size_t chunk = (rc0 + (c >> 1)) * nch + cc0 + (c & 1);
            *((s16x8*)&((unsigned short*)Cout)[chunk * 512 + lane * 8]) = v;
        }
    }
}

// ---------- Split-K reduce (FC2): out = x + bias + sum_s partial_s ----------
__global__ __launch_bounds__(256) void reduce_kernel(const unsigned short* __restrict__ p0,
                                                     const unsigned short* __restrict__ p1,
                                                     const unsigned short* __restrict__ p2,
                                                     const unsigned short* __restrict__ p3,
                                                     int S,
                                                     const float* __restrict__ x,
                                                     const float* __restrict__ bias,
                                                     float* __restrict__ out) {
    int i = (blockIdx.x * 256 + threadIdx.x) * 8;
    int col = i & (DIM - 1);
    float4 b0 = *((const float4*)(bias + col));
    float4 b1 = *((const float4*)(bias + col + 4));
    float4 x0 = *((const float4*)(x + i));
    float4 x1 = *((const float4*)(x + i + 4));
    float a[8] = {x0.x + b0.x, x0.y + b0.y, x0.z + b0.z, x0.w + b0.w,
                  x1.x + b1.x, x1.y + b1.y, x1.z + b1.z, x1.w + b1.w};
    const unsigned short* ps[4] = {p0, p1, p2, p3};
    for (int s = 0; s < S; ++s) {
        uint4 w = *((const uint4*)(ps[s] + i));
        a[0] += blo(w.x); a[1] += bhi(w.x);
        a[2] += blo(w.y); a[3] += bhi(w.y);
        a[4] += blo(w.z); a[5] += bhi(w.z);
        a[6] += blo(w.w); a[7] += bhi(w.w);
    }
    *((float4*)(out + i))     = make_float4(a[0], a[1], a[2], a[3]);
    *((float4*)(out + i + 4)) = make_float4(a[4], a[5], a[6], a[7]);
}

// ------------- MFMA flash attention, QBLK=64 (4 blocks/CU), no-max softmax -------------
// 1024 blocks: xcd = L&7, qt = (L>>3)&15, bh = (L&7) + 8*(L>>7). Each wave owns 16 q-rows.
// l (row sums) via extra PV MFMA against static e0-column block. setprio around MFMA (T5).
__global__ __launch_bounds__(256) void fattn_mfma(const unsigned short* __restrict__ qkv,
                                                  const unsigned short* __restrict__ Vt,
                                                  unsigned short* __restrict__ out) {
    __shared__ __align__(16) short Qs[4096];     // 8 chunks: 64 rows x 64 d
    __shared__ __align__(16) short Ks[4096];     // 8 chunks: 64 krows x 64 d
    __shared__ __align__(16) short Vs[4096];     // 8 chunks
    __shared__ __align__(16) short Ps[64 * 72];  // P tile, padded stride
    __shared__ __align__(16) short OnesB[512];   // B-frag: col0 = 1.0, rest 0

    const int tid = threadIdx.x, lane = tid & 63, wave = tid >> 6;
    const int lr = lane & 15, lq = lane >> 4;
    const int L = blockIdx.x;
    const int idx = L >> 3;
    const int qt = idx & 15;
    const int bh = (L & 7) + 8 * (idx >> 4);
    const int b = bh >> 4, h = bh & 15;
    const int q0 = qt * 64;

    {
        s16x8 z = (s16x8){0,0,0,0,0,0,0,0};
        if (lr == 0) { z[0] = (short)0x3F80; z[1] = (short)0x3F80;
                       z[2] = (short)0x3F80; z[3] = (short)0x3F80;
                       z[4] = (short)0x3F80; z[5] = (short)0x3F80;
                       z[6] = (short)0x3F80; z[7] = (short)0x3F80; }
        if (wave == 0) *((s16x8*)&OnesB[lane * 8]) = z;
    }

    // Q: 8 chunks (row-chunk = wave, d-chunk = j)
    #pragma unroll
    for (int j = 0; j < 2; ++j) {
        int cid = wave * 2 + j;
        const unsigned short* g = qkv + ((size_t)(((b * SEQ + q0) >> 4) + (cid >> 1)) * 96
                                         + 2 * h + (cid & 1)) * 512 + lane * 8;
        gload_lds16(g, &Qs[cid * 512]);
    }

    const unsigned short* kg_[2]; const unsigned short* vg_[2];
    short *kl_[2], *vl_[2];
    #pragma unroll
    for (int j = 0; j < 2; ++j) {
        int cid = wave * 2 + j;
        kg_[j] = qkv + ((size_t)(((b * SEQ) >> 4) + (cid >> 1)) * 96
                        + 32 + 2 * h + (cid & 1)) * 512 + lane * 8;
        vg_[j] = Vt + (size_t)bh * 65536
                 + ((size_t)(cid >> 1) * 32 + (cid & 1)) * 512 + lane * 8;
        kl_[j] = &Ks[cid * 512];
        vl_[j] = &Vs[cid * 512];
    }

    f32x4 osum[5];               // [4] = row-sum accumulator (l)
    #pragma unroll
    for (int d = 0; d < 5; ++d)
        osum[d] = (f32x4){0.f, 0.f, 0.f, 0.f};

    const float c = 0.125f * 1.44269504f;   // scale * log2(e)

    for (int k0 = 0; k0 < SEQ; k0 += 64) {
        #pragma unroll
        for (int j = 0; j < 2; ++j) {
            gload_lds16(kg_[j], kl_[j]);
            gload_lds16(vg_[j], vl_[j]);
            kg_[j] += 4 * 96 * 512;
            vg_[j] += 1024;
        }
        __syncthreads();

        f32x4 s[4];
        #pragma unroll
        for (int jb = 0; jb < 4; ++jb)
            s[jb] = (f32x4){0.f, 0.f, 0.f, 0.f};
        __builtin_amdgcn_s_setprio(1);
        #pragma unroll
        for (int kc = 0; kc < 2; ++kc) {
            s16x8 aq = *((const s16x8*)&Qs[(wave * 2 + kc) * 512 + lane * 8]);
            #pragma unroll
            for (int jb = 0; jb < 4; ++jb) {
                s16x8 bk = *((const s16x8*)&Ks[(jb * 2 + kc) * 512 + lane * 8]);
                s[jb] = __builtin_amdgcn_mfma_f32_16x16x32_bf16(aq, bk, s[jb], 0, 0, 0);
            }
        }
        __builtin_amdgcn_s_setprio(0);

        // p = exp2(s * c) -> Ps rows (wave-private 16 rows, no shuffles)
        #pragma unroll
        for (int r = 0; r < 4; ++r) {
            int prow = wave * 16 + lq * 4 + r;
            #pragma unroll
            for (int jb = 0; jb < 4; ++jb)
                Ps[prow * 72 + jb * 16 + lr] = (short)f2b(exp2f(s[jb][r] * c));
        }

        // O += P [V | e0]
        __builtin_amdgcn_s_setprio(1);
        #pragma unroll
        for (int kc = 0; kc < 2; ++kc) {
            s16x8 ap = *((const s16x8*)&Ps[(wave * 16 + lr) * 72 + kc * 32 + lq * 8]);
            #pragma unroll
            for (int db = 0; db < 4; ++db) {
                s16x8 bv = *((const s16x8*)&Vs[(db * 2 + kc) * 512 + lane * 8]);
                osum[db] = __builtin_amdgcn_mfma_f32_16x16x32_bf16(ap, bv, osum[db], 0, 0, 0);
            }
            s16x8 bo = *((const s16x8*)&OnesB[lane * 8]);
            osum[4] = __builtin_amdgcn_mfma_f32_16x16x32_bf16(ap, bo, osum[4], 0, 0, 0);
        }
        __builtin_amdgcn_s_setprio(0);
        __syncthreads();
    }

    // epilogue: l sits at col 0 (lanes lq*16); broadcast and divide
    {
        int qrow = q0 + wave * 16 + lq * 4;
        #pragma unroll
        for (int r = 0; r < 4; ++r) {
            float lsum = __shfl(osum[4][r], lane & 48, 64);
            float inv = 1.0f / lsum;
            int row = b * SEQ + qrow + r;
            #pragma unroll
            for (int db = 0; db < 4; ++db)
                out[tidx(row, h * 64 + db * 16 + lr, DIM)] = f2b(osum[db][r] * inv);
        }
    }
}

extern "C" void kernel_launch(void* const* d_in, const int* in_sizes, int n_in,
                              void* d_out, int out_size, void* d_ws, size_t ws_size,
                              hipStream_t stream) {
    const float* x      = (const float*)d_in[0];
    const float* ln1_g  = (const float*)d_in[1];
    const float* ln1_b  = (const float*)d_in[2];
    const float* ln2_g  = (const float*)d_in[3];
    const float* ln2_b  = (const float*)d_in[4];
    const float* qkv_w  = (const float*)d_in[5];
    const float* qkv_b  = (const float*)d_in[6];
    const float* proj_w = (const float*)d_in[7];
    const float* proj_b = (const float*)d_in[8];
    const float* fc1_w  = (const float*)d_in[9];
    const float* fc1_b  = (const float*)d_in[10];
    const float* fc2_w  = (const float*)d_in[11];
    const float* fc2_b  = (const float*)d_in[12];
    float* out = (float*)d_out;

    // workspace layout (MiB), 72 total — liveness-packed
    char* ws = (char*)d_ws;
    unsigned short* wT_fc2  = (unsigned short*)(ws);
    unsigned short* wT_qkv  = (unsigned short*)(ws + (8u  << 20));
    unsigned short* wT_proj = (unsigned short*)(ws + (14u << 20));
    unsigned short* qkvbuf  = (unsigned short*)(ws + (16u << 20));
    unsigned short* Vt      = (unsigned short*)(ws + (40u << 20));
    unsigned short* attnout = (unsigned short*)(ws + (48u << 20));
    unsigned short* lnout   = (unsigned short*)(ws + (56u << 20));
    unsigned short* wT_fc1  = (unsigned short*)(ws + (64u << 20));
    unsigned short* gelu    = (unsigned short*)(ws + (16u << 20));
    unsigned short* pp0 = (unsigned short*)(ws + (16u << 20));
    unsigned short* pp1 = (unsigned short*)(ws + (24u << 20));
    unsigned short* fp0 = (unsigned short*)(ws + (48u << 20));
    unsigned short* fp1 = (unsigned short*)(ws + (56u << 20));
    unsigned short* fp2 = (unsigned short*)(ws + (64u << 20));
    unsigned short* fp3 = (unsigned short*)(ws + (8u  << 20));

    // 0+1) prep: LN1(x) -> lnout tiled  AND  all 4 weight converts (one launch)
    prep_kernel<<<ROWS + 3072, 256, 0, stream>>>(
        x, ln1_g, ln1_b, lnout,
        qkv_w, wT_qkv, proj_w, wT_proj, fc1_w, wT_fc1, fc2_w, wT_fc2);
    // 2) qkv = h1 @ qkv_w + qkv_b -> Q,K tiled; V -> Vt tiled (fused transpose)
    mfma_gemm<<<dim3(ROWS / 128, 3 * DIM / 128, 1), 256, 0, stream>>>(
        lnout, wT_qkv, qkv_b, qkvbuf, Vt, nullptr, nullptr, nullptr, nullptr,
        ROWS, 3 * DIM, DIM, DIM, 0);
    // 3) o = mfma flash attention (QBLK=64, 1024 blocks) -> attnout tiled
    fattn_mfma<<<(SEQ / 64) * BATCH * HEADS, 256, 0, stream>>>(qkvbuf, Vt, attnout);
    // 4) proj split-K (S=2): partials = o @ proj_w (plain bf16)
    mfma_gemm<<<dim3(ROWS / 128, DIM / 128, 2), 256, 0, stream>>>(
        attnout, wT_proj, proj_b, nullptr, nullptr, pp0, pp1, nullptr, nullptr,
        ROWS, DIM, DIM, DIM / 2, 3);
    // 4b+5) x1 = x + sum + proj_b -> d_out; h2 = LN2(x1) -> lnout tiled  (FUSED)
    reduce_ln<<<ROWS, 256, 0, stream>>>(pp0, pp1, x, proj_b, ln2_g, ln2_b, out, lnout);
    // 6) g = gelu(h2 @ fc1_w + fc1_b) -> bf16 tiled  [4096 x 4096]
    mfma_gemm<<<dim3(ROWS / 128, HIDDEN / 128, 1), 256, 0, stream>>>(
        lnout, wT_fc1, fc1_b, gelu, nullptr, nullptr, nullptr, nullptr, nullptr,
        ROWS, HIDDEN, DIM, DIM, 1);
    // 7) FC2 split-K (S=4): partials = g @ fc2_w (plain bf16)
    mfma_gemm<<<dim3(ROWS / 128, DIM / 128, 4), 256, 0, stream>>>(
        gelu, wT_fc2, fc2_b, nullptr, nullptr, fp0, fp1, fp2, fp3,
        ROWS, DIM, HIDDEN, HIDDEN / 4, 3);
    // 7b) out = x1 + sum(partials) + fc2_b -> d_out (fp32, in-place residual)
    reduce_kernel<<<ROWS * DIM / 2048, 256, 0, stream>>>(
        fp0, fp1, fp2, fp3, 4, out, fc2_b, out);
}